// Round 2
// baseline (339.934 us; speedup 1.0000x reference)
//
#include <hip/hip_runtime.h>
#include <math.h>

#define Bx 16
#define Cx 64
#define Hx 128
#define Wx 128
#define HWx (Hx * Wx)

#define TW 32
#define TH 8
#define CCH 8
#define HALO_W (TW + 2)
#define HALO_H (TH + 2)
#define CPLANE (HALO_H * HALO_W)          // 340
#define CHUNK_ELEMS (CCH * CPLANE)        // 2720
#define NPF ((CHUNK_ELEMS + 255) / 256)   // 11
#define NCHUNK (Cx / CCH)                 // 8

// workspace layout (float offsets)
#define WS_CWT   0                         // 64*64      = 4096
#define WS_GPACK 4096                      // 64*72      = 4608
#define WS_KERN  8704                      // 16*2304    = 36864
#define WS_ATT   45568                     // 16*256     = 4096
// total 49664 floats = 194.4 KB

// ---------------- prep: hypernetwork + weight repacking ----------------
__global__ __launch_bounds__(256)
void da_prep(const float* __restrict__ x_deg,
             const float* __restrict__ kw1,
             const float* __restrict__ kw2,
             const float* __restrict__ convw,
             const float* __restrict__ ca_w1,
             const float* __restrict__ ca_w2,
             const float* __restrict__ g1w,
             const float* __restrict__ g2w,
             float* __restrict__ ws)
{
    const int b = blockIdx.x;
    const int tid = threadIdx.x;

    if (b == Bx) {  // weight repack block
        for (int i = tid; i < 4096; i += 256) {           // cwT[c*64+o] = convw[o*64+c]
            const int o = i >> 6, c = i & 63;
            ws[WS_CWT + c * 64 + o] = convw[o * 64 + c];
        }
        for (int i = tid; i < 4608; i += 256) {           // gpack[c*72 + r*18 + g*9 + k]
            const int c = i / 72;
            int rem = i - c * 72;
            const int r = rem / 18; rem -= r * 18;
            const int g = rem / 9;
            const int k = rem - g * 9;
            const float* src = g ? g2w : g1w;
            ws[WS_GPACK + i] = src[(r * Cx + c) * 9 + k];
        }
        return;
    }

    __shared__ float h1[16];
    __shared__ float a1[16];
    if (tid < 32) {
        const int j = tid & 15;
        const float* wsrc = (tid < 16) ? (kw1 + j * Cx) : (ca_w1 + j * Cx);
        float acc = 0.f;
        #pragma unroll 8
        for (int c = 0; c < Cx; ++c) acc = fmaf(x_deg[b * Cx + c], wsrc[c], acc);
        acc = acc > 0.f ? acc : 0.1f * acc;               // leaky_relu 0.1
        if (tid < 16) h1[j] = acc; else a1[j] = acc;
    }
    __syncthreads();

    // kern[b,g,o=c*9+k] -> ws layout [c*36 + k*4 + g]  (identical math/order to passing round)
    for (int o4 = tid; o4 < 4 * 576; o4 += 256) {
        const int g = o4 / 576;
        const int o = o4 - g * 576;
        float acc = 0.f;
        #pragma unroll
        for (int i = 0; i < 4; ++i)
            acc = fmaf(h1[g * 4 + i], kw2[(g * 576 + o) * 4 + i], acc);
        const int c = o / 9;
        const int k = o - c * 9;
        ws[WS_KERN + b * 2304 + c * 36 + k * 4 + g] = acc;
    }
    // att -> ws layout [c*4 + r]
    {
        const int r = tid >> 6;
        const int c = tid & 63;
        float acc = 0.f;
        #pragma unroll
        for (int i = 0; i < 4; ++i)
            acc = fmaf(a1[r * 4 + i], ca_w2[(r * Cx + c) * 4 + i], acc);
        ws[WS_ATT + b * 256 + c * 4 + r] = 1.f / (1.f + expf(-acc));
    }
}

// ---------------- main fused kernel ----------------
__global__ __launch_bounds__(256, 4)
void da_main(const float* __restrict__ x0,
             const float* __restrict__ ws,
             const float* __restrict__ g1b,
             const float* __restrict__ g2b,
             const float* __restrict__ convb,
             float* __restrict__ out)
{
    const int b  = blockIdx.z;
    const int h0 = blockIdx.y * TH;
    const int w0 = blockIdx.x * TW;
    const int tid = threadIdx.x;
    const int tx = tid & (TW - 1);
    const int ty = tid >> 5;

    __shared__ float sx[2][CHUNK_ELEMS];   // ping-pong x tile (with halo)
    __shared__ float skern[2304];          // [c][k][r]
    __shared__ float satt[256];            // [c][r]

    // --- per-thread staging map (computed once) ---
    int goff[NPF];
    unsigned vmask = 0u;
    #pragma unroll
    for (int i = 0; i < NPF; ++i) {
        const int e = tid + i * 256;
        const int cc  = e / CPLANE;
        const int rem = e - cc * CPLANE;
        const int row = rem / HALO_W;
        const int col = rem - row * HALO_W;
        const int gh = h0 - 1 + row;
        const int gw = w0 - 1 + col;
        goff[i] = cc * HWx + gh * Wx + gw;
        if (e < CHUNK_ELEMS && (unsigned)gh < Hx && (unsigned)gw < Wx)
            vmask |= (1u << i);
    }

    const float* xb    = x0 + (size_t)b * Cx * HWx;
    const float* kws   = ws + WS_KERN + b * 2304;
    const float* aws   = ws + WS_ATT  + b * 256;
    const float* gpack = ws + WS_GPACK;
    const float* cwT   = ws + WS_CWT;

    // --- prologue: stage skern/satt (L2-hot) + chunk 0 ---
    float pk[10];
    #pragma unroll
    for (int i = 0; i < 9; ++i) pk[i] = kws[tid + i * 256];
    pk[9] = aws[tid];
    float pf[NPF];
    #pragma unroll
    for (int i = 0; i < NPF; ++i)
        pf[i] = (vmask >> i & 1u) ? xb[goff[i]] : 0.f;
    #pragma unroll
    for (int i = 0; i < 9; ++i) skern[tid + i * 256] = pk[i];
    satt[tid] = pk[9];
    #pragma unroll
    for (int i = 0; i < NPF; ++i) {
        const int e = tid + i * 256;
        if (e < CHUNK_ELEMS) sx[0][e] = pf[i];
    }
    __syncthreads();

    float ga[8];
    #pragma unroll
    for (int r = 0; r < 4; ++r) { ga[r] = g1b[r]; ga[4 + r] = g2b[r]; }
    int r1 = 0, r2 = 0;

    float y[Cx];
    #pragma unroll
    for (int o = 0; o < Cx; ++o) y[o] = 0.f;

    // --- unified pipelined loop: t<8 = guide pass, t>=8 = main pass ---
    for (int t = 0; t < 2 * NCHUNK; ++t) {
        const int buf = t & 1;

        // prefetch next chunk into registers (latency hidden under compute)
        if (t < 2 * NCHUNK - 1) {
            const int nch = (t + 1) & (NCHUNK - 1);
            const float* src = xb + (size_t)nch * CCH * HWx;
            #pragma unroll
            for (int i = 0; i < NPF; ++i)
                pf[i] = (vmask >> i & 1u) ? src[goff[i]] : 0.f;
        }

        const int ch = t & (NCHUNK - 1);
        if (t < NCHUNK) {
            // ---- guide convs (bit-identical order to passing round) ----
            float pg[8] = {0.f, 0.f, 0.f, 0.f, 0.f, 0.f, 0.f, 0.f};
            #pragma unroll
            for (int cc = 0; cc < CCH; ++cc) {
                const int c = ch * CCH + cc;
                float n[9];
                #pragma unroll
                for (int kh = 0; kh < 3; ++kh)
                    #pragma unroll
                    for (int kw = 0; kw < 3; ++kw)
                        n[kh * 3 + kw] = sx[buf][cc * CPLANE + (ty + kh) * HALO_W + (tx + kw)];
                const float* gp = gpack + c * 72;   // one contiguous scalar run
                #pragma unroll
                for (int r = 0; r < 4; ++r) {
                    float s1 = 0.f, s2 = 0.f;
                    #pragma unroll
                    for (int k = 0; k < 9; ++k) {
                        s1 = fmaf(n[k], gp[r * 18 + k],     s1);
                        s2 = fmaf(n[k], gp[r * 18 + 9 + k], s2);
                    }
                    pg[r]     += s1;
                    pg[4 + r] += s2;
                }
            }
            #pragma unroll
            for (int i = 0; i < 8; ++i) ga[i] += pg[i];

            if (t == NCHUNK - 1) {   // argmax (first-max ties, same as before)
                float m = ga[0];
                #pragma unroll
                for (int r = 1; r < 4; ++r) if (ga[r] > m) { m = ga[r]; r1 = r; }
                float m2 = ga[4];
                #pragma unroll
                for (int r = 1; r < 4; ++r) if (ga[4 + r] > m2) { m2 = ga[4 + r]; r2 = r; }
            }
        } else {
            // ---- routed depthwise + 1x1 accumulate ----
            #pragma unroll
            for (int cc = 0; cc < CCH; ++cc) {
                const int c = ch * CCH + cc;
                float n[9];
                #pragma unroll
                for (int kh = 0; kh < 3; ++kh)
                    #pragma unroll
                    for (int kw = 0; kw < 3; ++kw)
                        n[kh * 3 + kw] = sx[buf][cc * CPLANE + (ty + kh) * HALO_W + (tx + kw)];

                float dw = 0.f;
                #pragma unroll
                for (int k = 0; k < 9; ++k)
                    dw = fmaf(n[k], skern[c * 36 + k * 4 + r1], dw);
                const float routed = dw > 0.f ? dw : 0.1f * dw;

                const float* cw = cwT + c * 64;     // contiguous scalar run
                #pragma unroll
                for (int o = 0; o < Cx; ++o)
                    y[o] = fmaf(cw[o], routed, y[o]);
            }
        }

        // write prefetched chunk into the other buffer
        if (t < 2 * NCHUNK - 1) {
            #pragma unroll
            for (int i = 0; i < NPF; ++i) {
                const int e = tid + i * 256;
                if (e < CHUNK_ELEMS) sx[buf ^ 1][e] = pf[i];
            }
        }
        __syncthreads();
    }

    // --- epilogue: bias + CA branch + store (identical to passing round) ---
    const int hh = h0 + ty;
    const int ww = w0 + tx;
    float* op = out + (size_t)b * Cx * HWx + hh * Wx + ww;
    const float* xp = xb + hh * Wx + ww;
    #pragma unroll
    for (int o = 0; o < Cx; ++o) {
        const float v = y[o] + convb[o] + xp[(size_t)o * HWx] * satt[o * 4 + r2];
        op[(size_t)o * HWx] = v;
    }
}

extern "C" void kernel_launch(void* const* d_in, const int* in_sizes, int n_in,
                              void* d_out, int out_size, void* d_ws, size_t ws_size,
                              hipStream_t stream) {
    const float* x0     = (const float*)d_in[0];
    const float* x_deg  = (const float*)d_in[1];
    const float* kw1    = (const float*)d_in[2];
    const float* kw2    = (const float*)d_in[3];
    const float* convw  = (const float*)d_in[4];
    const float* convb  = (const float*)d_in[5];
    const float* ca_w1  = (const float*)d_in[6];
    const float* ca_w2  = (const float*)d_in[7];
    const float* g1w    = (const float*)d_in[8];
    const float* g1b    = (const float*)d_in[9];
    const float* g2w    = (const float*)d_in[10];
    const float* g2b    = (const float*)d_in[11];
    float* outp = (float*)d_out;
    float* wsf  = (float*)d_ws;

    da_prep<<<Bx + 1, 256, 0, stream>>>(x_deg, kw1, kw2, convw, ca_w1, ca_w2,
                                        g1w, g2w, wsf);

    dim3 grid(Wx / TW, Hx / TH, Bx);   // 4 x 16 x 16 = 1024 blocks
    da_main<<<grid, 256, 0, stream>>>(x0, wsf, g1b, g2b, convb, outp);
}